// Round 1
// baseline (1232.856 us; speedup 1.0000x reference)
//
#include <hip/hip_runtime.h>
#include <stdint.h>

#define DD 64          // embed dim
#define LPAD 130       // 128 + 2 pad (columns of 2D x D weights)
#define SPAD 66        // 64 + 2 pad  (columns of D x D weights)

__device__ __forceinline__ float bcl(float v, int l) {
    // broadcast lane l of v to all lanes (constant l -> v_readlane -> SGPR)
    return __int_as_float(__builtin_amdgcn_readlane(__float_as_int(v), l));
}
__device__ __forceinline__ uint16_t f2bf(float f) {
    uint32_t u = __float_as_uint(f);
    u += 0x7FFFu + ((u >> 16) & 1u);   // round-to-nearest-even
    return (uint16_t)(u >> 16);
}
__device__ __forceinline__ float bflo(uint32_t w) { return __uint_as_float(w << 16); }
__device__ __forceinline__ float bfhi(uint32_t w) { return __uint_as_float(w & 0xFFFF0000u); }

__global__ __launch_bounds__(256) void uvagg_kernel(
    const int* __restrict__ nodes, const int* __restrict__ history_uv,
    const int* __restrict__ history_r, const int* __restrict__ hist_len,
    const float* __restrict__ v2e, const float* __restrict__ u2e,
    const float* __restrict__ r2e,
    const float* __restrict__ W1, const float* __restrict__ b1,
    const float* __restrict__ W2, const float* __restrict__ b2,
    const float* __restrict__ A1, const float* __restrict__ ab1,
    const float* __restrict__ A2, const float* __restrict__ ab2,
    const float* __restrict__ A3, const float* __restrict__ ab3,
    float* __restrict__ out, int N, int L)
{
    // Weights in LDS, bf16, column-major with +2 pad:
    //   col-major so lane d reads its column; pair of k's per ds_read_b32.
    //   bank(lane) = (lane*65 + k/2) % 32 -> lanes hit banks 0..31 twice: free.
    __shared__ uint16_t W1c[DD * LPAD];
    __shared__ uint16_t W2c[DD * SPAD];
    __shared__ uint16_t A1c[DD * LPAD];
    __shared__ uint16_t A2c[DD * SPAD];

    const int tid = threadIdx.x;
    for (int i = tid; i < 128 * DD; i += 256) {
        int k = i >> 6, c = i & 63;
        W1c[c * LPAD + k] = f2bf(W1[i]);
        A1c[c * LPAD + k] = f2bf(A1[i]);
    }
    for (int i = tid; i < DD * DD; i += 256) {
        int k = i >> 6, c = i & 63;
        W2c[c * SPAD + k] = f2bf(W2[i]);
        A2c[c * SPAD + k] = f2bf(A2[i]);
    }
    __syncthreads();

    const int lane = tid & 63;
    const int wid  = tid >> 6;
    const int node = blockIdx.x * 4 + wid;
    if (node >= N) return;

    int hl = hist_len[node];
    hl = __builtin_amdgcn_readfirstlane(min(hl, L));
    const int un = __builtin_amdgcn_readfirstlane(nodes[node]);

    const float urep = u2e[(size_t)un * DD + lane];
    const float b1v = b1[lane], b2v = b2[lane];
    const float ab1v = ab1[lane], ab2v = ab2[lane];
    const float a3v = A3[lane];
    const float ab3v = ab3[0];

    const int* __restrict__ huv = history_uv + (size_t)node * L;
    const int* __restrict__ hr  = history_r  + (size_t)node * L;

    const uint16_t* __restrict__ c1 = W1c + lane * LPAD;
    const uint16_t* __restrict__ c2 = W2c + lane * SPAD;
    const uint16_t* __restrict__ c3 = A1c + lane * LPAD;
    const uint16_t* __restrict__ c4 = A2c + lane * SPAD;

    float m = -1e30f, Z = 0.0f, accO = 0.0f;

    for (int l = 0; l < hl; ++l) {
        const int iu = __builtin_amdgcn_readfirstlane(huv[l]);
        const int ir = __builtin_amdgcn_readfirstlane(hr[l]);
        const float euv = v2e[(size_t)iu * DD + lane];
        const float er  = r2e[ir * DD + lane];

        // ---- stage 1: x1 = relu([euv|er] @ W1 + b1), lane owns column `lane`
        float x1 = b1v;
        #pragma unroll
        for (int k = 0; k < 64; k += 2) {
            uint32_t w = *(const uint32_t*)(c1 + k);
            x1 = fmaf(bcl(euv, k),     bflo(w), x1);
            x1 = fmaf(bcl(euv, k + 1), bfhi(w), x1);
        }
        #pragma unroll
        for (int k = 0; k < 64; k += 2) {
            uint32_t w = *(const uint32_t*)(c1 + 64 + k);
            x1 = fmaf(bcl(er, k),     bflo(w), x1);
            x1 = fmaf(bcl(er, k + 1), bfhi(w), x1);
        }
        x1 = fmaxf(x1, 0.0f);

        // ---- stage 2: o = relu(x1 @ W2 + b2)
        float o = b2v;
        #pragma unroll
        for (int k = 0; k < 64; k += 2) {
            uint32_t w = *(const uint32_t*)(c2 + k);
            o = fmaf(bcl(x1, k),     bflo(w), o);
            o = fmaf(bcl(x1, k + 1), bfhi(w), o);
        }
        o = fmaxf(o, 0.0f);

        // ---- stage 3: h1 = relu([o|urep] @ A1 + ab1)
        float h1 = ab1v;
        #pragma unroll
        for (int k = 0; k < 64; k += 2) {
            uint32_t w = *(const uint32_t*)(c3 + k);
            h1 = fmaf(bcl(o, k),     bflo(w), h1);
            h1 = fmaf(bcl(o, k + 1), bfhi(w), h1);
        }
        #pragma unroll
        for (int k = 0; k < 64; k += 2) {
            uint32_t w = *(const uint32_t*)(c3 + 64 + k);
            h1 = fmaf(bcl(urep, k),     bflo(w), h1);
            h1 = fmaf(bcl(urep, k + 1), bfhi(w), h1);
        }
        h1 = fmaxf(h1, 0.0f);

        // ---- stage 4: h2 = relu(h1 @ A2 + ab2)
        float h2 = ab2v;
        #pragma unroll
        for (int k = 0; k < 64; k += 2) {
            uint32_t w = *(const uint32_t*)(c4 + k);
            h2 = fmaf(bcl(h1, k),     bflo(w), h2);
            h2 = fmaf(bcl(h1, k + 1), bfhi(w), h2);
        }
        h2 = fmaxf(h2, 0.0f);

        // ---- attention logit s = h2 . A3 + ab3  (wave reduce)
        float part = h2 * a3v;
        #pragma unroll
        for (int off = 32; off; off >>= 1)
            part += __shfl_xor(part, off, 64);
        const float s = part + ab3v;

        // ---- online softmax accumulation of o
        if (s > m) {
            const float c = __expf(m - s);  // first iter: exp(-huge)=0 -> resets
            accO *= c; Z *= c; m = s;
        }
        const float p = __expf(s - m);
        Z += p;
        accO = fmaf(p, o, accO);
    }

    out[(size_t)node * DD + lane] = accO / Z;
}

extern "C" void kernel_launch(void* const* d_in, const int* in_sizes, int n_in,
                              void* d_out, int out_size, void* d_ws, size_t ws_size,
                              hipStream_t stream) {
    const int*   nodes = (const int*)d_in[0];
    const int*   huv   = (const int*)d_in[1];
    const int*   hr    = (const int*)d_in[2];
    const int*   hlen  = (const int*)d_in[3];
    const float* v2e   = (const float*)d_in[4];
    const float* u2e   = (const float*)d_in[5];
    const float* r2e   = (const float*)d_in[6];
    const float* W1    = (const float*)d_in[7];
    const float* b1    = (const float*)d_in[8];
    const float* W2    = (const float*)d_in[9];
    const float* b2    = (const float*)d_in[10];
    const float* A1    = (const float*)d_in[11];
    const float* ab1   = (const float*)d_in[12];
    const float* A2    = (const float*)d_in[13];
    const float* ab2   = (const float*)d_in[14];
    const float* A3    = (const float*)d_in[15];
    const float* ab3   = (const float*)d_in[16];
    float* out = (float*)d_out;

    const int N = in_sizes[0];
    const int L = in_sizes[1] / N;

    dim3 grid((N + 3) / 4), block(256);
    hipLaunchKernelGGL(uvagg_kernel, grid, block, 0, stream,
                       nodes, huv, hr, hlen, v2e, u2e, r2e,
                       W1, b1, W2, b2, A1, ab1, A2, ab2, A3, ab3,
                       out, N, L);
}

// Round 2
// 69.971 us; speedup vs baseline: 17.6195x; 17.6195x over previous
//
#include <hip/hip_runtime.h>
#include <hip/hip_bf16.h>
#include <stdint.h>

typedef short bfx8 __attribute__((ext_vector_type(8)));
typedef float f32x4 __attribute__((ext_vector_type(4)));

#define MFMA16(a, b, c) __builtin_amdgcn_mfma_f32_16x16x32_bf16(a, b, c, 0, 0, 0)

__device__ __forceinline__ uint16_t f2bf(float f) {
    uint32_t u = __float_as_uint(f);
    u += 0x7FFFu + ((u >> 16) & 1u);   // RNE
    return (uint16_t)(u >> 16);
}
__device__ __forceinline__ uint32_t pk2(float a, float b) {
    __hip_bfloat162 h = __float22bfloat162_rn(make_float2(a, b)); // low=a, high=b
    union { __hip_bfloat162 h; uint32_t u; } cv; cv.h = h; return cv.u;
}
__device__ __forceinline__ bfx8 pack8(const float4 a, const float4 b) {
    union { bfx8 v; uint32_t u[4]; } r;
    r.u[0] = pk2(a.x, a.y); r.u[1] = pk2(a.z, a.w);
    r.u[2] = pk2(b.x, b.y); r.u[3] = pk2(b.z, b.w);
    return r.v;
}
// Read one MFMA fragment (8 contiguous-k bf16) from a swizzled [row][k] LDS array.
// Physical byte-in-row = logical ^ ((row&7)<<4)  (bits 4-6 -> bank spread).
__device__ __forceinline__ bfx8 ldfrag(const uint8_t* base, int row, int rowB, int kbyte, int g) {
    int off = (kbyte + 16 * g) ^ ((row & 7) << 4);
    return *(const bfx8*)(base + row * rowB + off);
}
__device__ __forceinline__ float4 ld4(const float* p) { return *(const float4*)p; }

__global__ __launch_bounds__(512) void uvagg_mfma(
    const int* __restrict__ nodes, const int* __restrict__ huv,
    const int* __restrict__ hr, const int* __restrict__ hlen,
    const float* __restrict__ v2e, const float* __restrict__ u2e,
    const float* __restrict__ r2e,
    const float* __restrict__ W1, const float* __restrict__ b1,
    const float* __restrict__ W2, const float* __restrict__ b2,
    const float* __restrict__ A1, const float* __restrict__ ab1,
    const float* __restrict__ A2, const float* __restrict__ ab2,
    const float* __restrict__ A3, const float* __restrict__ ab3f,
    float* __restrict__ out, int N, int L, int nwaves)
{
    // Weights as bf16, transposed [d][k] (k contiguous), XOR-swizzled rows.
    __shared__ __align__(16) uint8_t W1s[64 * 256];
    __shared__ __align__(16) uint8_t A1s[64 * 256];
    __shared__ __align__(16) uint8_t W2s[64 * 128];
    __shared__ __align__(16) uint8_t A2s[64 * 128];
    __shared__ __align__(16) uint8_t tiles[8][2048];   // per-wave 16x64 bf16 bounce tile
    __shared__ __align__(16) float cb[324];            // b1|b2|ab1|ab2|A3|ab3

    const int tid = threadIdx.x;
    for (int i = tid; i < 128 * 64; i += 512) {
        int k = i >> 6, d = i & 63;
        uint32_t off = (uint32_t)(2 * k) ^ ((d & 7) << 4);
        *(uint16_t*)(W1s + d * 256 + off) = f2bf(W1[i]);
        *(uint16_t*)(A1s + d * 256 + off) = f2bf(A1[i]);
    }
    for (int i = tid; i < 64 * 64; i += 512) {
        int k = i >> 6, d = i & 63;
        uint32_t off = (uint32_t)(2 * k) ^ ((d & 7) << 4);
        *(uint16_t*)(W2s + d * 128 + off) = f2bf(W2[i]);
        *(uint16_t*)(A2s + d * 128 + off) = f2bf(A2[i]);
    }
    if (tid < 64)        cb[tid]       = b1[tid];
    else if (tid < 128)  cb[tid]       = b2[tid - 64];
    else if (tid < 192)  cb[tid]       = ab1[tid - 128];
    else if (tid < 256)  cb[tid]       = ab2[tid - 192];
    else if (tid < 320)  cb[tid]       = A3[tid - 256];
    else if (tid == 320) cb[320]       = ab3f[0];
    __syncthreads();

    const int lane = tid & 63;
    const int wid  = tid >> 6;
    const int s    = lane & 15;   // slot-in-tile / matrix column
    const int g    = lane >> 4;   // k-group
    uint8_t* tb = tiles[wid];
    const float ab3 = cb[320];

    const int gwave = blockIdx.x * 8 + wid;

    for (int node = gwave; node < N; node += nwaves) {
        int hl = __builtin_amdgcn_readfirstlane(min(hlen[node], L));
        int un = __builtin_amdgcn_readfirstlane(nodes[node]);

        // urep B-frags (k = 64..127 of attention input), constant over slots
        const float* ur = u2e + (size_t)un * 64;
        bfx8 uf2 = pack8(ld4(ur + 8 * g),      ld4(ur + 8 * g + 4));
        bfx8 uf3 = pack8(ld4(ur + 32 + 8 * g), ld4(ur + 36 + 8 * g));

        const int clamped = min(lane, L - 1);
        const int iu_all = huv[(size_t)node * L + clamped];
        const int ir_all = hr [(size_t)node * L + clamped];

        float m = -3.0e38f, Z = 0.0f;
        f32x4 accO[4];
        #pragma unroll
        for (int i = 0; i < 4; ++i) accO[i] = f32x4{0.f, 0.f, 0.f, 0.f};

        const int ntile = (hl + 15) >> 4;
        for (int tt = 0; tt < ntile; ++tt) {
            const int gslot = tt * 16 + s;
            const int iu = __shfl(iu_all, gslot, 64);
            const int ir = __shfl(ir_all, gslot, 64);
            const float* vr = v2e + (size_t)iu * 64;
            const float* rr = r2e + (size_t)ir * 64;
            // X B-frags: k 0..63 = e_uv, 64..127 = e_r
            bfx8 f0 = pack8(ld4(vr + 8 * g),      ld4(vr + 8 * g + 4));
            bfx8 f1 = pack8(ld4(vr + 32 + 8 * g), ld4(vr + 36 + 8 * g));
            bfx8 f2 = pack8(ld4(rr + 8 * g),      ld4(rr + 8 * g + 4));
            bfx8 f3 = pack8(ld4(rr + 32 + 8 * g), ld4(rr + 36 + 8 * g));

            // ---- stage 1: x1T = W1T @ XT   (+b1, relu)
            f32x4 ah[4];
            #pragma unroll
            for (int mt = 0; mt < 4; ++mt) {
                float4 bq = ld4(&cb[0 + mt * 16 + g * 4]);
                ah[mt] = f32x4{bq.x, bq.y, bq.z, bq.w};
            }
            #pragma unroll
            for (int mt = 0; mt < 4; ++mt) {
                int row = mt * 16 + s;
                ah[mt] = MFMA16(ldfrag(W1s, row, 256, 0,   g), f0, ah[mt]);
                ah[mt] = MFMA16(ldfrag(W1s, row, 256, 64,  g), f1, ah[mt]);
                ah[mt] = MFMA16(ldfrag(W1s, row, 256, 128, g), f2, ah[mt]);
                ah[mt] = MFMA16(ldfrag(W1s, row, 256, 192, g), f3, ah[mt]);
            }
            #pragma unroll
            for (int mt = 0; mt < 4; ++mt) {
                f32x4 v = ah[mt];
                float v0 = fmaxf(v[0], 0.f), v1 = fmaxf(v[1], 0.f);
                float v2 = fmaxf(v[2], 0.f), v3 = fmaxf(v[3], 0.f);
                uint32_t off = (uint32_t)(mt * 32 + g * 8) ^ ((s & 7) << 4);
                *(uint2*)(tb + s * 128 + off) = uint2{pk2(v0, v1), pk2(v2, v3)};
            }
            asm volatile("s_waitcnt lgkmcnt(0)" ::: "memory");
            bfx8 x1a = ldfrag(tb, s, 128, 0,  g);
            bfx8 x1b = ldfrag(tb, s, 128, 64, g);

            // ---- stage 2: oT = W2T @ x1T  (+b2, relu) — keep fp32 in ao
            f32x4 ao[4];
            #pragma unroll
            for (int mt = 0; mt < 4; ++mt) {
                float4 bq = ld4(&cb[64 + mt * 16 + g * 4]);
                ao[mt] = f32x4{bq.x, bq.y, bq.z, bq.w};
            }
            #pragma unroll
            for (int mt = 0; mt < 4; ++mt) {
                int row = mt * 16 + s;
                ao[mt] = MFMA16(ldfrag(W2s, row, 128, 0,  g), x1a, ao[mt]);
                ao[mt] = MFMA16(ldfrag(W2s, row, 128, 64, g), x1b, ao[mt]);
            }
            #pragma unroll
            for (int mt = 0; mt < 4; ++mt) {
                #pragma unroll
                for (int r2 = 0; r2 < 4; ++r2) ao[mt][r2] = fmaxf(ao[mt][r2], 0.f);
                uint32_t off = (uint32_t)(mt * 32 + g * 8) ^ ((s & 7) << 4);
                *(uint2*)(tb + s * 128 + off) = uint2{pk2(ao[mt][0], ao[mt][1]), pk2(ao[mt][2], ao[mt][3])};
            }
            asm volatile("s_waitcnt lgkmcnt(0)" ::: "memory");
            bfx8 oa = ldfrag(tb, s, 128, 0,  g);
            bfx8 ob = ldfrag(tb, s, 128, 64, g);

            // ---- stage 3: h1T = A1T @ [oT; urepT]  (+ab1, relu)
            f32x4 h[4];
            #pragma unroll
            for (int mt = 0; mt < 4; ++mt) {
                float4 bq = ld4(&cb[128 + mt * 16 + g * 4]);
                h[mt] = f32x4{bq.x, bq.y, bq.z, bq.w};
            }
            #pragma unroll
            for (int mt = 0; mt < 4; ++mt) {
                int row = mt * 16 + s;
                h[mt] = MFMA16(ldfrag(A1s, row, 256, 0,   g), oa,  h[mt]);
                h[mt] = MFMA16(ldfrag(A1s, row, 256, 64,  g), ob,  h[mt]);
                h[mt] = MFMA16(ldfrag(A1s, row, 256, 128, g), uf2, h[mt]);
                h[mt] = MFMA16(ldfrag(A1s, row, 256, 192, g), uf3, h[mt]);
            }
            #pragma unroll
            for (int mt = 0; mt < 4; ++mt) {
                f32x4 v = h[mt];
                float v0 = fmaxf(v[0], 0.f), v1 = fmaxf(v[1], 0.f);
                float v2 = fmaxf(v[2], 0.f), v3 = fmaxf(v[3], 0.f);
                uint32_t off = (uint32_t)(mt * 32 + g * 8) ^ ((s & 7) << 4);
                *(uint2*)(tb + s * 128 + off) = uint2{pk2(v0, v1), pk2(v2, v3)};
            }
            asm volatile("s_waitcnt lgkmcnt(0)" ::: "memory");
            bfx8 h1a = ldfrag(tb, s, 128, 0,  g);
            bfx8 h1b = ldfrag(tb, s, 128, 64, g);

            // ---- stage 4: h2T = A2T @ h1T  (+ab2, relu)
            f32x4 h2[4];
            #pragma unroll
            for (int mt = 0; mt < 4; ++mt) {
                float4 bq = ld4(&cb[192 + mt * 16 + g * 4]);
                h2[mt] = f32x4{bq.x, bq.y, bq.z, bq.w};
            }
            #pragma unroll
            for (int mt = 0; mt < 4; ++mt) {
                int row = mt * 16 + s;
                h2[mt] = MFMA16(ldfrag(A2s, row, 128, 0,  g), h1a, h2[mt]);
                h2[mt] = MFMA16(ldfrag(A2s, row, 128, 64, g), h1b, h2[mt]);
            }

            // ---- attention logit: s[slot] = sum_d relu(h2)[d][slot]*A3[d] + ab3
            float part = 0.f;
            #pragma unroll
            for (int mt = 0; mt < 4; ++mt) {
                float4 aq = ld4(&cb[256 + mt * 16 + g * 4]);
                part += fmaxf(h2[mt][0], 0.f) * aq.x + fmaxf(h2[mt][1], 0.f) * aq.y
                      + fmaxf(h2[mt][2], 0.f) * aq.z + fmaxf(h2[mt][3], 0.f) * aq.w;
            }
            part += __shfl_xor(part, 16, 64);
            part += __shfl_xor(part, 32, 64);
            float sl = part + ab3;
            if (gslot >= hl) sl = -3.0e38f;

            // ---- online softmax over slots
            float tm = sl;
            tm = fmaxf(tm, __shfl_xor(tm, 1, 64));
            tm = fmaxf(tm, __shfl_xor(tm, 2, 64));
            tm = fmaxf(tm, __shfl_xor(tm, 4, 64));
            tm = fmaxf(tm, __shfl_xor(tm, 8, 64));
            float mnew = fmaxf(m, tm);
            float sc = __expf(m - mnew);
            float p  = __expf(sl - mnew);
            float zt = p;
            zt += __shfl_xor(zt, 1, 64);
            zt += __shfl_xor(zt, 2, 64);
            zt += __shfl_xor(zt, 4, 64);
            zt += __shfl_xor(zt, 8, 64);
            Z = Z * sc + zt;
            #pragma unroll
            for (int mt = 0; mt < 4; ++mt)
                #pragma unroll
                for (int r2 = 0; r2 < 4; ++r2)
                    accO[mt][r2] = accO[mt][r2] * sc + p * ao[mt][r2];
            m = mnew;
        }

        // reduce weighted sum over the 16 slot-lanes
        #pragma unroll
        for (int mt = 0; mt < 4; ++mt) {
            #pragma unroll
            for (int r2 = 0; r2 < 4; ++r2) {
                float v = accO[mt][r2];
                v += __shfl_xor(v, 1, 64);
                v += __shfl_xor(v, 2, 64);
                v += __shfl_xor(v, 4, 64);
                v += __shfl_xor(v, 8, 64);
                accO[mt][r2] = v;
            }
        }
        const float inv = 1.0f / Z;
        if (s == 0) {
            float* op = out + (size_t)node * 64 + g * 4;
            #pragma unroll
            for (int mt = 0; mt < 4; ++mt) {
                *(float4*)(op + mt * 16) = make_float4(accO[mt][0] * inv, accO[mt][1] * inv,
                                                       accO[mt][2] * inv, accO[mt][3] * inv);
            }
        }
    }
}

extern "C" void kernel_launch(void* const* d_in, const int* in_sizes, int n_in,
                              void* d_out, int out_size, void* d_ws, size_t ws_size,
                              hipStream_t stream) {
    const int*   nodes = (const int*)d_in[0];
    const int*   huv   = (const int*)d_in[1];
    const int*   hr    = (const int*)d_in[2];
    const int*   hlen  = (const int*)d_in[3];
    const float* v2e   = (const float*)d_in[4];
    const float* u2e   = (const float*)d_in[5];
    const float* r2e   = (const float*)d_in[6];
    const float* W1    = (const float*)d_in[7];
    const float* b1    = (const float*)d_in[8];
    const float* W2    = (const float*)d_in[9];
    const float* b2    = (const float*)d_in[10];
    const float* A1    = (const float*)d_in[11];
    const float* ab1   = (const float*)d_in[12];
    const float* A2    = (const float*)d_in[13];
    const float* ab2   = (const float*)d_in[14];
    const float* A3    = (const float*)d_in[15];
    const float* ab3   = (const float*)d_in[16];
    float* out = (float*)d_out;

    const int N = in_sizes[0];
    const int L = in_sizes[1] / N;
    const int blocks = 512;
    const int nwaves = blocks * 8;

    hipLaunchKernelGGL(uvagg_mfma, dim3(blocks), dim3(512), 0, stream,
                       nodes, huv, hr, hlen, v2e, u2e, r2e,
                       W1, b1, W2, b2, A1, ab1, A2, ab2, A3, ab3,
                       out, N, L, nwaves);
}